// Round 1
// baseline (205.229 us; speedup 1.0000x reference)
//
#include <hip/hip_runtime.h>
#include <hip/hip_bf16.h>
#include <stdint.h>

typedef _Float16 f16;
typedef _Float16 f16x8 __attribute__((ext_vector_type(8)));
typedef float    f32x4 __attribute__((ext_vector_type(4)));

#define GLDS16(g, l) __builtin_amdgcn_global_load_lds(                        \
    (const __attribute__((address_space(1))) void*)(g),                      \
    (__attribute__((address_space(3))) void*)(l), 16, 0, 0)

constexpr int T  = 2048;
constexpr int B  = 2;
constexpr int H  = 16;
constexpr int DM = 1024;
constexpr int MT = B * T;       // 4096 token rows
constexpr int NQKV = 3 * DM;    // 3072

// ---------------------------------------------------------------- tables
__global__ void k_tables(float* __restrict__ cosT, float* __restrict__ sinT) {
    int idx = blockIdx.x * 256 + threadIdx.x;       // T*32 = 65536
    if (idx >= T * 32) return;
    int t = idx >> 5, f = idx & 31;
    // inv_freq = 10000^(-f/32) = 2^(-f * log2(1e4)/32)
    float inv = exp2f(-(float)f * 0.41524101186092034f);
    float ang = (float)t * inv;
    cosT[idx] = cosf(ang);
    sinT[idx] = sinf(ang);
}

// ---------------------------------------------------------------- cast x
__global__ void k_cast_x(const float* __restrict__ x, f16* __restrict__ xh) {
    int i = blockIdx.x * 256 + threadIdx.x;         // per 8 elems
    const float4* p = (const float4*)x;
    float4 a = p[i * 2], b = p[i * 2 + 1];
    f16x8 o = { (f16)a.x, (f16)a.y, (f16)a.z, (f16)a.w,
                (f16)b.x, (f16)b.y, (f16)b.z, (f16)b.w };
    ((f16x8*)xh)[i] = o;
}

// ------------------------------------------------- weight cast+transpose
// dst is B^T layout: WT[n][k] = W[k][n], fp16
__global__ void k_wt(const float* __restrict__ Wq, const float* __restrict__ Wk,
                     const float* __restrict__ Wv, const float* __restrict__ Wo,
                     f16* __restrict__ WqkvT, f16* __restrict__ WoT) {
    __shared__ float tile[32][33];
    int z = blockIdx.z;
    const float* src = (z == 0) ? Wq : (z == 1) ? Wk : (z == 2) ? Wv : Wo;
    f16* dst = (z < 3) ? (WqkvT + (size_t)z * DM * DM) : WoT;
    int bx = blockIdx.x * 32, by = blockIdx.y * 32;   // bx: n, by: k
    int tx = threadIdx.x, ty = threadIdx.y;
#pragma unroll
    for (int j = 0; j < 4; j++)
        tile[ty + j * 8][tx] = src[(size_t)(by + ty + j * 8) * DM + bx + tx];
    __syncthreads();
#pragma unroll
    for (int j = 0; j < 4; j++)
        dst[(size_t)(bx + ty + j * 8) * DM + by + tx] = (f16)tile[tx][ty + j * 8];
}

// ---------------------------------------------------------------- GEMM
// C[M][N] = A[M][K] @ Bt[N][K]^T  (+ bias), 128x128 tile, BK=64, 4 waves 2x2
template <bool OUTF32>
__global__ __launch_bounds__(256) void k_gemm(const f16* __restrict__ A,
                                              const f16* __restrict__ Bt,
                                              void* __restrict__ Cv,
                                              const float* __restrict__ bias,
                                              int M, int N, int K) {
    __shared__ f16 sA[128 * 64];
    __shared__ f16 sB[128 * 64];
    const int tid = threadIdx.x, w = tid >> 6, l = tid & 63;
    const int m0 = blockIdx.x * 128, n0 = blockIdx.y * 128;
    const int wm = w >> 1, wn = w & 1;
    const int lrow = tid >> 3;   // staging: row within 32-row slab
    const int lch  = tid & 7;    // staging: chunk' (8-elem granule)
    f32x4 acc[4][4] = {};

    for (int kt = 0; kt < K; kt += 64) {
        __syncthreads();
#pragma unroll
        for (int i = 0; i < 4; i++) {
            int row = i * 32 + lrow;
            int c = lch ^ (row & 7);                 // inverse-swizzled source
            GLDS16(A + (size_t)(m0 + row) * K + kt + c * 8, &sA[i * 2048 + w * 512]);
        }
#pragma unroll
        for (int i = 0; i < 4; i++) {
            int row = i * 32 + lrow;
            int c = lch ^ (row & 7);
            GLDS16(Bt + (size_t)(n0 + row) * K + kt + c * 8, &sB[i * 2048 + w * 512]);
        }
        __syncthreads();
#pragma unroll
        for (int ks = 0; ks < 2; ks++) {
            f16x8 af[4], bf[4];
#pragma unroll
            for (int mi = 0; mi < 4; mi++) {
                int row = wm * 64 + mi * 16 + (l & 15);
                int c = (ks * 4 + (l >> 4)) ^ (row & 7);
                af[mi] = *(const f16x8*)&sA[row * 64 + c * 8];
            }
#pragma unroll
            for (int ni = 0; ni < 4; ni++) {
                int row = wn * 64 + ni * 16 + (l & 15);
                int c = (ks * 4 + (l >> 4)) ^ (row & 7);
                bf[ni] = *(const f16x8*)&sB[row * 64 + c * 8];
            }
#pragma unroll
            for (int ni = 0; ni < 4; ni++)
#pragma unroll
                for (int mi = 0; mi < 4; mi++)
                    acc[mi][ni] = __builtin_amdgcn_mfma_f32_16x16x32_f16(
                        af[mi], bf[ni], acc[mi][ni], 0, 0, 0);
        }
    }
    const int rb = m0 + wm * 64 + ((l >> 4) << 2);
    const int cb = n0 + wn * 64 + (l & 15);
#pragma unroll
    for (int ni = 0; ni < 4; ni++) {
        int col = cb + ni * 16;
        float bz = bias ? bias[col] : 0.f;
#pragma unroll
        for (int mi = 0; mi < 4; mi++) {
#pragma unroll
            for (int r = 0; r < 4; r++) {
                int row = rb + mi * 16 + r;
                float v = acc[mi][ni][r] + bz;
                if (OUTF32) ((float*)Cv)[(size_t)row * N + col] = v;
                else        ((f16*)Cv)[(size_t)row * N + col] = (f16)v;
            }
        }
    }
}

// --------------------------------------------- RoPE + bias + head permute
// QKV[4096][3072] -> QA[bh][t][64] (roped, x1/8), KA[bh][t][64] (roped),
//                    VT[bh][64][t] (transposed)
__global__ __launch_bounds__(256) void k_rope(const f16* __restrict__ QKV,
        const float* __restrict__ cosT, const float* __restrict__ sinT,
        const float* __restrict__ bq, const float* __restrict__ bk,
        const float* __restrict__ bv,
        f16* __restrict__ QA, f16* __restrict__ KA, f16* __restrict__ VT) {
    const int tt = blockIdx.x, bh = blockIdx.y;
    const int b = bh >> 4, h = bh & 15;
    const int tid = threadIdx.x;
    const int t_loc = tid >> 2;
    const int f0 = (tid & 3) * 8;
    const int t_abs = tt * 64 + t_loc;
    const size_t tg = (size_t)b * T + t_abs;
    const size_t qkvrow = tg * NQKV;

    float cs[8], sn[8];
#pragma unroll
    for (int e = 0; e < 8; e++) {
        cs[e] = cosT[t_abs * 32 + f0 + e];
        sn[e] = sinT[t_abs * 32 + f0 + e];
    }
    // Q (pre-scaled by 1/8 = 1/sqrt(HEAD_DIM))
    {
        f16x8 x1 = *(const f16x8*)(QKV + qkvrow + h * 64 + f0);
        f16x8 x2 = *(const f16x8*)(QKV + qkvrow + h * 64 + 32 + f0);
        f16x8 o1, o2;
#pragma unroll
        for (int e = 0; e < 8; e++) {
            float a = (float)x1[e] + bq[h * 64 + f0 + e];
            float c2 = (float)x2[e] + bq[h * 64 + 32 + f0 + e];
            o1[e] = (f16)((a * cs[e] - c2 * sn[e]) * 0.125f);
            o2[e] = (f16)((a * sn[e] + c2 * cs[e]) * 0.125f);
        }
        f16* qa = QA + ((size_t)bh * T + t_abs) * 64;
        *(f16x8*)(qa + f0) = o1;
        *(f16x8*)(qa + 32 + f0) = o2;
    }
    // K
    {
        f16x8 x1 = *(const f16x8*)(QKV + qkvrow + DM + h * 64 + f0);
        f16x8 x2 = *(const f16x8*)(QKV + qkvrow + DM + h * 64 + 32 + f0);
        f16x8 o1, o2;
#pragma unroll
        for (int e = 0; e < 8; e++) {
            float a = (float)x1[e] + bk[h * 64 + f0 + e];
            float c2 = (float)x2[e] + bk[h * 64 + 32 + f0 + e];
            o1[e] = (f16)(a * cs[e] - c2 * sn[e]);
            o2[e] = (f16)(a * sn[e] + c2 * cs[e]);
        }
        f16* ka = KA + ((size_t)bh * T + t_abs) * 64;
        *(f16x8*)(ka + f0) = o1;
        *(f16x8*)(ka + 32 + f0) = o2;
    }
    // V transpose via LDS
    __shared__ f16 sT[64][80];
    {
        int dch = tid & 3;
#pragma unroll
        for (int q2 = 0; q2 < 2; q2++) {
            f16x8 v = *(const f16x8*)(QKV + qkvrow + 2 * DM + h * 64 + dch * 16 + q2 * 8);
#pragma unroll
            for (int e = 0; e < 8; e++) {
                int d = dch * 16 + q2 * 8 + e;
                sT[d][t_loc] = (f16)((float)v[e] + bv[h * 64 + d]);
            }
        }
    }
    __syncthreads();
    {
        int d = tid >> 2, tc = (tid & 3) * 16;
        f16* vt = VT + ((size_t)bh * 64 + d) * T + tt * 64 + tc;
        *(f16x8*)(vt)     = *(const f16x8*)&sT[d][tc];
        *(f16x8*)(vt + 8) = *(const f16x8*)&sT[d][tc + 8];
    }
}

// -------------------------------------------------------- flash attention
// grid (T/128, B*H); 4 waves x 32 q-rows; KV tiles of 64; online softmax
__global__ __launch_bounds__(256) void k_attn(const f16* __restrict__ QA,
                                              const f16* __restrict__ KA,
                                              const f16* __restrict__ VT,
                                              f16* __restrict__ CTX) {
    __shared__ f16 sK[64 * 64];
    __shared__ f16 sV[64 * 64];
    __shared__ f16 sP[4 * 32 * 64];
    const int tid = threadIdx.x, w = tid >> 6, l = tid & 63;
    const int qb = blockIdx.x, bh = blockIdx.y;
    const int b = bh >> 4, h = bh & 15;
    const size_t qbase = (size_t)bh * T * 64;
    const int q0 = qb * 128 + w * 32;
    const int lrow = tid >> 3, lch = tid & 7;

    // Q fragments in registers (A-layout): [mfrag][kstep]
    f16x8 qf[2][2];
#pragma unroll
    for (int mi = 0; mi < 2; mi++)
#pragma unroll
        for (int ks = 0; ks < 2; ks++)
            qf[mi][ks] = *(const f16x8*)(QA + qbase +
                (size_t)(q0 + mi * 16 + (l & 15)) * 64 + ks * 32 + (l >> 4) * 8);

    f32x4 ctx[2][4] = {};
    float mrun[2][4], lrun[2][4];
#pragma unroll
    for (int mi = 0; mi < 2; mi++)
#pragma unroll
        for (int r = 0; r < 4; r++) { mrun[mi][r] = -1e30f; lrun[mi][r] = 0.f; }

    for (int kv = 0; kv < T; kv += 64) {
        __syncthreads();
#pragma unroll
        for (int i = 0; i < 2; i++) {
            int row = i * 32 + lrow;
            int c = lch ^ (row & 7);
            GLDS16(KA + qbase + (size_t)(kv + row) * 64 + c * 8, &sK[i * 2048 + w * 512]);
            GLDS16(VT + qbase + (size_t)row * T + kv + c * 8,    &sV[i * 2048 + w * 512]);
        }
        __syncthreads();

        // S = Q K^T  (Q pre-scaled by 1/8)
        f32x4 sf[2][4] = {};
#pragma unroll
        for (int ks = 0; ks < 2; ks++) {
            f16x8 kf[4];
#pragma unroll
            for (int ni = 0; ni < 4; ni++) {
                int row = ni * 16 + (l & 15);
                int c = (ks * 4 + (l >> 4)) ^ (row & 7);
                kf[ni] = *(const f16x8*)&sK[row * 64 + c * 8];
            }
#pragma unroll
            for (int ni = 0; ni < 4; ni++)
#pragma unroll
                for (int mi = 0; mi < 2; mi++)
                    sf[mi][ni] = __builtin_amdgcn_mfma_f32_16x16x32_f16(
                        qf[mi][ks], kf[ni], sf[mi][ni], 0, 0, 0);
        }

        // online softmax (fp32)
        float sc[2][4];
#pragma unroll
        for (int mi = 0; mi < 2; mi++) {
#pragma unroll
            for (int r = 0; r < 4; r++) {
                float v = fmaxf(fmaxf(sf[mi][0][r], sf[mi][1][r]),
                                fmaxf(sf[mi][2][r], sf[mi][3][r]));
#pragma unroll
                for (int msk = 1; msk < 16; msk <<= 1)
                    v = fmaxf(v, __shfl_xor(v, msk));
                float mn = fmaxf(mrun[mi][r], v);
                sc[mi][r] = __expf(mrun[mi][r] - mn);
                mrun[mi][r] = mn;
                float s0 = 0.f;
#pragma unroll
                for (int ni = 0; ni < 4; ni++) {
                    float p = __expf(sf[mi][ni][r] - mn);
                    sf[mi][ni][r] = p;
                    s0 += p;
                }
#pragma unroll
                for (int msk = 1; msk < 16; msk <<= 1)
                    s0 += __shfl_xor(s0, msk);
                lrun[mi][r] = lrun[mi][r] * sc[mi][r] + s0;
            }
        }
#pragma unroll
        for (int mi = 0; mi < 2; mi++)
#pragma unroll
            for (int di = 0; di < 4; di++)
#pragma unroll
                for (int r = 0; r < 4; r++)
                    ctx[mi][di][r] *= sc[mi][r];

        // P (C-layout) -> LDS (swizzled) -> A-layout fragments
#pragma unroll
        for (int mi = 0; mi < 2; mi++) {
#pragma unroll
            for (int ni = 0; ni < 4; ni++) {
                int chunk = ni * 2 + ((l & 15) >> 3);
#pragma unroll
                for (int r = 0; r < 4; r++) {
                    int q = mi * 16 + ((l >> 4) << 2) + r;
                    int c = chunk ^ (q & 7);
                    sP[w * 2048 + q * 64 + c * 8 + (l & 7)] = (f16)sf[mi][ni][r];
                }
            }
        }
        // PV
#pragma unroll
        for (int ks = 0; ks < 2; ks++) {
            f16x8 pf[2], vf[4];
#pragma unroll
            for (int mi = 0; mi < 2; mi++) {
                int row = mi * 16 + (l & 15);
                int c = (ks * 4 + (l >> 4)) ^ (row & 7);
                pf[mi] = *(const f16x8*)&sP[w * 2048 + row * 64 + c * 8];
            }
#pragma unroll
            for (int di = 0; di < 4; di++) {
                int row = di * 16 + (l & 15);
                int c = (ks * 4 + (l >> 4)) ^ (row & 7);
                vf[di] = *(const f16x8*)&sV[row * 64 + c * 8];
            }
#pragma unroll
            for (int di = 0; di < 4; di++)
#pragma unroll
                for (int mi = 0; mi < 2; mi++)
                    ctx[mi][di] = __builtin_amdgcn_mfma_f32_16x16x32_f16(
                        pf[mi], vf[di], ctx[mi][di], 0, 0, 0);
        }
    }

    // epilogue: ctx / l -> CTX[4096][1024] fp16
#pragma unroll
    for (int mi = 0; mi < 2; mi++) {
        float inv[4];
#pragma unroll
        for (int r = 0; r < 4; r++) inv[r] = 1.f / lrun[mi][r];
#pragma unroll
        for (int di = 0; di < 4; di++) {
            int col = h * 64 + di * 16 + (l & 15);
#pragma unroll
            for (int r = 0; r < 4; r++) {
                int trow = q0 + mi * 16 + ((l >> 4) << 2) + r;
                CTX[((size_t)b * T + trow) * DM + col] = (f16)(ctx[mi][di][r] * inv[r]);
            }
        }
    }
}

// ---------------------------------------------------------------- launch
extern "C" void kernel_launch(void* const* d_in, const int* in_sizes, int n_in,
                              void* d_out, int out_size, void* d_ws, size_t ws_size,
                              hipStream_t stream) {
    const float* x  = (const float*)d_in[0];
    const float* Wq = (const float*)d_in[1];
    const float* bq = (const float*)d_in[2];
    const float* Wk = (const float*)d_in[3];
    const float* bk = (const float*)d_in[4];
    const float* Wv = (const float*)d_in[5];
    const float* bv = (const float*)d_in[6];
    const float* Wo = (const float*)d_in[7];
    const float* bo = (const float*)d_in[8];

    char* ws = (char*)d_ws;
    f16*   xh    = (f16*)(ws + 0);              // 8 MB (dead after GEMM1)
    f16*   ctx   = (f16*)(ws + 0);              // reuses xh region
    f16*   WqkvT = (f16*)(ws + ((size_t)8  << 20));   // 6 MB
    f16*   WoT   = (f16*)(ws + ((size_t)14 << 20));   // 2 MB
    f16*   QKV   = (f16*)(ws + ((size_t)16 << 20));   // 24 MB
    f16*   QA    = (f16*)(ws + ((size_t)40 << 20));   // 8 MB
    f16*   KA    = (f16*)(ws + ((size_t)48 << 20));   // 8 MB
    f16*   VT    = (f16*)(ws + ((size_t)56 << 20));   // 8 MB
    float* cosT  = (float*)(ws + ((size_t)64 << 20)); // 256 KB
    float* sinT  = cosT + T * 32;                     // 256 KB

    k_tables<<<dim3(256), dim3(256), 0, stream>>>(cosT, sinT);
    k_cast_x<<<dim3(2048), dim3(256), 0, stream>>>(x, xh);
    k_wt<<<dim3(32, 32, 4), dim3(32, 8), 0, stream>>>(Wq, Wk, Wv, Wo, WqkvT, WoT);
    k_gemm<false><<<dim3(MT / 128, NQKV / 128), dim3(256), 0, stream>>>(
        xh, WqkvT, (void*)QKV, nullptr, MT, NQKV, DM);
    k_rope<<<dim3(T / 64, B * H), dim3(256), 0, stream>>>(
        QKV, cosT, sinT, bq, bk, bv, QA, KA, VT);
    k_attn<<<dim3(T / 128, B * H), dim3(256), 0, stream>>>(QA, KA, VT, ctx);
    k_gemm<true><<<dim3(MT / 128, DM / 128), dim3(256), 0, stream>>>(
        ctx, WoT, d_out, bo, MT, DM, DM);
}

// Round 3
// 157.960 us; speedup vs baseline: 1.2993x; 1.2993x over previous
//
#include <hip/hip_runtime.h>
#include <hip/hip_bf16.h>
#include <stdint.h>

typedef _Float16 f16;
typedef _Float16 f16x8 __attribute__((ext_vector_type(8)));
typedef __fp16   fp16x2 __attribute__((ext_vector_type(2)));
typedef float    f32x4 __attribute__((ext_vector_type(4)));
typedef float    f32x16 __attribute__((ext_vector_type(16)));

#define GLDS16(g, l) __builtin_amdgcn_global_load_lds(                        \
    (const __attribute__((address_space(1))) void*)(g),                      \
    (__attribute__((address_space(3))) void*)(l), 16, 0, 0)

constexpr int T  = 2048;
constexpr int B  = 2;
constexpr int H  = 16;
constexpr int DM = 1024;
constexpr int MT = B * T;       // 4096 token rows
constexpr int NQKV = 3 * DM;    // 3072

// ---------------------------------------------------------------- tables
__global__ void k_tables(float* __restrict__ cosT, float* __restrict__ sinT) {
    int idx = blockIdx.x * 256 + threadIdx.x;       // T*32 = 65536
    if (idx >= T * 32) return;
    int t = idx >> 5, f = idx & 31;
    float inv = exp2f(-(float)f * 0.41524101186092034f);
    float ang = (float)t * inv;
    cosT[idx] = cosf(ang);
    sinT[idx] = sinf(ang);
}

// ---------------------------------------------------------------- cast x
__global__ void k_cast_x(const float* __restrict__ x, f16* __restrict__ xh) {
    int i = blockIdx.x * 256 + threadIdx.x;         // per 8 elems
    const float4* p = (const float4*)x;
    float4 a = p[i * 2], b = p[i * 2 + 1];
    f16x8 o = { (f16)a.x, (f16)a.y, (f16)a.z, (f16)a.w,
                (f16)b.x, (f16)b.y, (f16)b.z, (f16)b.w };
    ((f16x8*)xh)[i] = o;
}

// ------------------------------------------------- weight cast+transpose
__global__ void k_wt(const float* __restrict__ Wq, const float* __restrict__ Wk,
                     const float* __restrict__ Wv, const float* __restrict__ Wo,
                     f16* __restrict__ WqkvT, f16* __restrict__ WoT) {
    __shared__ float tile[32][33];
    int z = blockIdx.z;
    const float* src = (z == 0) ? Wq : (z == 1) ? Wk : (z == 2) ? Wv : Wo;
    f16* dst = (z < 3) ? (WqkvT + (size_t)z * DM * DM) : WoT;
    int bx = blockIdx.x * 32, by = blockIdx.y * 32;
    int tx = threadIdx.x, ty = threadIdx.y;
#pragma unroll
    for (int j = 0; j < 4; j++)
        tile[ty + j * 8][tx] = src[(size_t)(by + ty + j * 8) * DM + bx + tx];
    __syncthreads();
#pragma unroll
    for (int j = 0; j < 4; j++)
        dst[(size_t)(bx + ty + j * 8) * DM + by + tx] = (f16)tile[tx][ty + j * 8];
}

// ---------------------------------------------------------------- GEMM
template <bool OUTF32>
__global__ __launch_bounds__(256) void k_gemm(const f16* __restrict__ A,
                                              const f16* __restrict__ Bt,
                                              void* __restrict__ Cv,
                                              const float* __restrict__ bias,
                                              int M, int N, int K) {
    __shared__ f16 sA[128 * 64];
    __shared__ f16 sB[128 * 64];
    const int tid = threadIdx.x, w = tid >> 6, l = tid & 63;
    const int m0 = blockIdx.x * 128, n0 = blockIdx.y * 128;
    const int wm = w >> 1, wn = w & 1;
    const int lrow = tid >> 3;
    const int lch  = tid & 7;
    f32x4 acc[4][4] = {};

    for (int kt = 0; kt < K; kt += 64) {
        __syncthreads();
#pragma unroll
        for (int i = 0; i < 4; i++) {
            int row = i * 32 + lrow;
            int c = lch ^ (row & 7);
            GLDS16(A + (size_t)(m0 + row) * K + kt + c * 8, &sA[i * 2048 + w * 512]);
        }
#pragma unroll
        for (int i = 0; i < 4; i++) {
            int row = i * 32 + lrow;
            int c = lch ^ (row & 7);
            GLDS16(Bt + (size_t)(n0 + row) * K + kt + c * 8, &sB[i * 2048 + w * 512]);
        }
        __syncthreads();
#pragma unroll
        for (int ks = 0; ks < 2; ks++) {
            f16x8 af[4], bf[4];
#pragma unroll
            for (int mi = 0; mi < 4; mi++) {
                int row = wm * 64 + mi * 16 + (l & 15);
                int c = (ks * 4 + (l >> 4)) ^ (row & 7);
                af[mi] = *(const f16x8*)&sA[row * 64 + c * 8];
            }
#pragma unroll
            for (int ni = 0; ni < 4; ni++) {
                int row = wn * 64 + ni * 16 + (l & 15);
                int c = (ks * 4 + (l >> 4)) ^ (row & 7);
                bf[ni] = *(const f16x8*)&sB[row * 64 + c * 8];
            }
#pragma unroll
            for (int ni = 0; ni < 4; ni++)
#pragma unroll
                for (int mi = 0; mi < 4; mi++)
                    acc[mi][ni] = __builtin_amdgcn_mfma_f32_16x16x32_f16(
                        af[mi], bf[ni], acc[mi][ni], 0, 0, 0);
        }
    }
    const int rb = m0 + wm * 64 + ((l >> 4) << 2);
    const int cb = n0 + wn * 64 + (l & 15);
#pragma unroll
    for (int ni = 0; ni < 4; ni++) {
        int col = cb + ni * 16;
        float bz = bias ? bias[col] : 0.f;
#pragma unroll
        for (int mi = 0; mi < 4; mi++) {
#pragma unroll
            for (int r = 0; r < 4; r++) {
                int row = rb + mi * 16 + r;
                float v = acc[mi][ni][r] + bz;
                if (OUTF32) ((float*)Cv)[(size_t)row * N + col] = v;
                else        ((f16*)Cv)[(size_t)row * N + col] = (f16)v;
            }
        }
    }
}

// --------------------------------------------- RoPE + bias + head permute
__global__ __launch_bounds__(256) void k_rope(const f16* __restrict__ QKV,
        const float* __restrict__ cosT, const float* __restrict__ sinT,
        const float* __restrict__ bq, const float* __restrict__ bk,
        const float* __restrict__ bv,
        f16* __restrict__ QA, f16* __restrict__ KA, f16* __restrict__ VT) {
    const int tt = blockIdx.x, bh = blockIdx.y;
    const int b = bh >> 4, h = bh & 15;
    const int tid = threadIdx.x;
    const int t_loc = tid >> 2;
    const int f0 = (tid & 3) * 8;
    const int t_abs = tt * 64 + t_loc;
    const size_t tg = (size_t)b * T + t_abs;
    const size_t qkvrow = tg * NQKV;

    float cs[8], sn[8];
#pragma unroll
    for (int e = 0; e < 8; e++) {
        cs[e] = cosT[t_abs * 32 + f0 + e];
        sn[e] = sinT[t_abs * 32 + f0 + e];
    }
    {
        f16x8 x1 = *(const f16x8*)(QKV + qkvrow + h * 64 + f0);
        f16x8 x2 = *(const f16x8*)(QKV + qkvrow + h * 64 + 32 + f0);
        f16x8 o1, o2;
#pragma unroll
        for (int e = 0; e < 8; e++) {
            float a = (float)x1[e] + bq[h * 64 + f0 + e];
            float c2 = (float)x2[e] + bq[h * 64 + 32 + f0 + e];
            o1[e] = (f16)((a * cs[e] - c2 * sn[e]) * 0.125f);
            o2[e] = (f16)((a * sn[e] + c2 * cs[e]) * 0.125f);
        }
        f16* qa = QA + ((size_t)bh * T + t_abs) * 64;
        *(f16x8*)(qa + f0) = o1;
        *(f16x8*)(qa + 32 + f0) = o2;
    }
    {
        f16x8 x1 = *(const f16x8*)(QKV + qkvrow + DM + h * 64 + f0);
        f16x8 x2 = *(const f16x8*)(QKV + qkvrow + DM + h * 64 + 32 + f0);
        f16x8 o1, o2;
#pragma unroll
        for (int e = 0; e < 8; e++) {
            float a = (float)x1[e] + bk[h * 64 + f0 + e];
            float c2 = (float)x2[e] + bk[h * 64 + 32 + f0 + e];
            o1[e] = (f16)(a * cs[e] - c2 * sn[e]);
            o2[e] = (f16)(a * sn[e] + c2 * cs[e]);
        }
        f16* ka = KA + ((size_t)bh * T + t_abs) * 64;
        *(f16x8*)(ka + f0) = o1;
        *(f16x8*)(ka + 32 + f0) = o2;
    }
    __shared__ f16 sT[64][80];
    {
        int dch = tid & 3;
#pragma unroll
        for (int q2 = 0; q2 < 2; q2++) {
            f16x8 v = *(const f16x8*)(QKV + qkvrow + 2 * DM + h * 64 + dch * 16 + q2 * 8);
#pragma unroll
            for (int e = 0; e < 8; e++) {
                int d = dch * 16 + q2 * 8 + e;
                sT[d][t_loc] = (f16)((float)v[e] + bv[h * 64 + d]);
            }
        }
    }
    __syncthreads();
    {
        int d = tid >> 2, tc = (tid & 3) * 16;
        f16* vt = VT + ((size_t)bh * 64 + d) * T + tt * 64 + tc;
        *(f16x8*)(vt)     = *(const f16x8*)&sT[d][tc];
        *(f16x8*)(vt + 8) = *(const f16x8*)&sT[d][tc + 8];
    }
}

// -------------------------------------------------------- flash attention
// Swapped QK^T (S^T via mfma_32x32x16), in-register softmax (1 shfl per
// reduce), P->PV B-operand via cvt_pkrtz + permlane32_swap (T12), K/V
// double-buffered in LDS with single barrier per tile (T3-minimum).
static __device__ inline void plswap(unsigned &a, unsigned &b) {
    auto r = __builtin_amdgcn_permlane32_swap(a, b, false, false);
    a = (unsigned)r[0]; b = (unsigned)r[1];
}

static __device__ inline unsigned pk16(float a, float b) {
    union { fp16x2 h; unsigned u; } cv;
    cv.h = __builtin_amdgcn_cvt_pkrtz(a, b);
    return cv.u;
}

__global__ __launch_bounds__(256) void k_attn(const f16* __restrict__ QA,
                                              const f16* __restrict__ KA,
                                              const f16* __restrict__ VT,
                                              f16* __restrict__ CTX) {
    __shared__ __align__(16) f16 sK[2][64 * 64];
    __shared__ __align__(16) f16 sV[2][64 * 64];
    const int tid = threadIdx.x, w = tid >> 6, l = tid & 63;
    const int qb = blockIdx.x, bh = blockIdx.y;
    const int b = bh >> 4, h = bh & 15;
    const size_t qbase = (size_t)bh * T * 64;
    const int q0 = qb * 128 + w * 32;
    const int lq = l & 31, hi = l >> 5;

    // Q as B-operand fragments (col q = lq, contraction d = kc*16+hi*8+e)
    f16x8 qf[4];
#pragma unroll
    for (int kc = 0; kc < 4; kc++)
        qf[kc] = *(const f16x8*)(QA + qbase + (size_t)(q0 + lq) * 64 + kc * 16 + hi * 8);

    f32x16 octx[2] = {};
    float mrun = -1e30f, lrun = 0.f;

    const int srow = w * 2;  // this wave stages rows [srow*8 .. srow*8+15]
    const int lr8 = l >> 3, lc8 = l & 7;

    // prologue stage tile 0 into buf 0
#pragma unroll
    for (int j = 0; j < 2; j++) {
        int row = (srow + j) * 8 + lr8;
        int c = lc8 ^ (row & 7);
        GLDS16(KA + qbase + (size_t)row * 64 + c * 8, &sK[0][(srow + j) * 512]);
        GLDS16(VT + qbase + (size_t)row * T + c * 8,  &sV[0][(srow + j) * 512]);
    }
    __syncthreads();

    int cur = 0;
    for (int t = 0; t < T / 64; t++) {
        // stage next tile into the other buffer (flies under compute)
        if (t + 1 < T / 64) {
            int kv = (t + 1) * 64;
#pragma unroll
            for (int j = 0; j < 2; j++) {
                int row = (srow + j) * 8 + lr8;
                int c = lc8 ^ (row & 7);
                GLDS16(KA + qbase + (size_t)(kv + row) * 64 + c * 8,
                       &sK[cur ^ 1][(srow + j) * 512]);
                GLDS16(VT + qbase + (size_t)row * T + kv + c * 8,
                       &sV[cur ^ 1][(srow + j) * 512]);
            }
        }

        // ---- QK^T : S^T[k][q] (Q pre-scaled by 1/8)
        f32x16 st[2] = {};
#pragma unroll
        for (int kc = 0; kc < 4; kc++) {
            int ch = (kc * 2 + hi) ^ (lq & 7);
            f16x8 kf0 = *(const f16x8*)&sK[cur][lq * 64 + ch * 8];
            f16x8 kf1 = *(const f16x8*)&sK[cur][(32 + lq) * 64 + ch * 8];
            st[0] = __builtin_amdgcn_mfma_f32_32x32x16_f16(kf0, qf[kc], st[0], 0, 0, 0);
            st[1] = __builtin_amdgcn_mfma_f32_32x32x16_f16(kf1, qf[kc], st[1], 0, 0, 0);
        }

        // ---- online softmax: lane owns full column q
        float pm = st[0][0];
#pragma unroll
        for (int r = 1; r < 16; r++) pm = fmaxf(pm, st[0][r]);
#pragma unroll
        for (int r = 0; r < 16; r++) pm = fmaxf(pm, st[1][r]);
        pm = fmaxf(pm, __shfl_xor(pm, 32));
        float mn = fmaxf(mrun, pm);
        float sc = __expf(mrun - mn);
        mrun = mn;
        float rs = 0.f;
#pragma unroll
        for (int blk = 0; blk < 2; blk++)
#pragma unroll
            for (int r = 0; r < 16; r++) {
                float p = __expf(st[blk][r] - mn);
                st[blk][r] = p;
                rs += p;
            }
        rs += __shfl_xor(rs, 32);
        lrun = lrun * sc + rs;
#pragma unroll
        for (int blk = 0; blk < 2; blk++)
#pragma unroll
            for (int r = 0; r < 16; r++) octx[blk][r] *= sc;

        // ---- pack P to f16 pairs: pw[blk][j] holds k5 = 8*(j>>1)+4*hi+2*(j&1)+{0,1}
        unsigned pw[2][8];
#pragma unroll
        for (int blk = 0; blk < 2; blk++)
#pragma unroll
            for (int j = 0; j < 8; j++) {
                int r = 4 * (j >> 1) + 2 * (j & 1);
                pw[blk][j] = pk16(st[blk][r], st[blk][r + 1]);
            }

        // ---- PV: ctx^T[d][q] += V^T[d][k] * P^T[k][q]
#pragma unroll
        for (int ks = 0; ks < 4; ks++) {
            const int blk = ks >> 1, h4 = (ks & 1) * 4;
            unsigned m0 = pw[blk][h4 + 0], m2 = pw[blk][h4 + 2];
            plswap(m0, m2);
            unsigned m1 = pw[blk][h4 + 1], m3 = pw[blk][h4 + 3];
            plswap(m1, m3);
            union { unsigned u[4]; f16x8 v; } pb;
            pb.u[0] = m0; pb.u[1] = m1; pb.u[2] = m2; pb.u[3] = m3;
#pragma unroll
            for (int dblk = 0; dblk < 2; dblk++) {
                int row = dblk * 32 + lq;
                int ch = (ks * 2 + hi) ^ (row & 7);
                f16x8 vf = *(const f16x8*)&sV[cur][row * 64 + ch * 8];
                octx[dblk] = __builtin_amdgcn_mfma_f32_32x32x16_f16(
                    vf, pb.v, octx[dblk], 0, 0, 0);
            }
        }

        __syncthreads();   // drains staging vmcnt; next tile ready
        cur ^= 1;
    }

    // ---- epilogue: ctx^T / l -> CTX[b*T+q][h*64+d] (f16, paired stores)
    float inv = 1.f / lrun;
    f16* crow = CTX + ((size_t)b * T + q0 + lq) * DM + h * 64;
#pragma unroll
    for (int dblk = 0; dblk < 2; dblk++)
#pragma unroll
        for (int rp = 0; rp < 8; rp++) {
            int r = 2 * rp;
            int d = dblk * 32 + 8 * (rp >> 1) + 2 * (rp & 1) + 4 * hi;
            *(unsigned*)(crow + d) = pk16(octx[dblk][r] * inv,
                                          octx[dblk][r + 1] * inv);
        }
}

// ---------------------------------------------------------------- launch
extern "C" void kernel_launch(void* const* d_in, const int* in_sizes, int n_in,
                              void* d_out, int out_size, void* d_ws, size_t ws_size,
                              hipStream_t stream) {
    const float* x  = (const float*)d_in[0];
    const float* Wq = (const float*)d_in[1];
    const float* bq = (const float*)d_in[2];
    const float* Wk = (const float*)d_in[3];
    const float* bk = (const float*)d_in[4];
    const float* Wv = (const float*)d_in[5];
    const float* bv = (const float*)d_in[6];
    const float* Wo = (const float*)d_in[7];
    const float* bo = (const float*)d_in[8];

    char* ws = (char*)d_ws;
    f16*   xh    = (f16*)(ws + 0);
    f16*   ctx   = (f16*)(ws + 0);              // reuses xh region
    f16*   WqkvT = (f16*)(ws + ((size_t)8  << 20));
    f16*   WoT   = (f16*)(ws + ((size_t)14 << 20));
    f16*   QKV   = (f16*)(ws + ((size_t)16 << 20));
    f16*   QA    = (f16*)(ws + ((size_t)40 << 20));
    f16*   KA    = (f16*)(ws + ((size_t)48 << 20));
    f16*   VT    = (f16*)(ws + ((size_t)56 << 20));
    float* cosT  = (float*)(ws + ((size_t)64 << 20));
    float* sinT  = cosT + T * 32;

    k_tables<<<dim3(256), dim3(256), 0, stream>>>(cosT, sinT);
    k_cast_x<<<dim3(2048), dim3(256), 0, stream>>>(x, xh);
    k_wt<<<dim3(32, 32, 4), dim3(32, 8), 0, stream>>>(Wq, Wk, Wv, Wo, WqkvT, WoT);
    k_gemm<false><<<dim3(MT / 128, NQKV / 128), dim3(256), 0, stream>>>(
        xh, WqkvT, (void*)QKV, nullptr, MT, NQKV, DM);
    k_rope<<<dim3(T / 64, B * H), dim3(256), 0, stream>>>(
        QKV, cosT, sinT, bq, bk, bv, QA, KA, VT);
    k_attn<<<dim3(T / 128, B * H), dim3(256), 0, stream>>>(QA, KA, VT, ctx);
    k_gemm<true><<<dim3(MT / 128, DM / 128), dim3(256), 0, stream>>>(
        ctx, WoT, d_out, bo, MT, DM, DM);
}